// Round 2
// baseline (4873.339 us; speedup 1.0000x reference)
//
#include <hip/hip_runtime.h>
#include <cstdint>
#include <cstddef>

#define DIM 1024
#define NS 8
#define RANK 256
#define TSTEPS 1024
#define BB 8
#define NG 8          // workgroups per slot
#define DCH 128       // DIM / NG : d-slice per WG

typedef __attribute__((ext_vector_type(8))) short s8v;   // 8 x bf16
typedef __attribute__((ext_vector_type(4))) short s4v;   // 4 x bf16
typedef __attribute__((ext_vector_type(4))) float f4v;
typedef __attribute__((ext_vector_type(2))) float f2v;

__device__ __forceinline__ unsigned short f2bf(float f) {
  unsigned u = __float_as_uint(f);
  u += 0x7fffu + ((u >> 16) & 1u);          // round-to-nearest-even
  return (unsigned short)(u >> 16);
}
__device__ __forceinline__ float bf2f(unsigned short h) {
  return __uint_as_float(((unsigned)h) << 16);
}

// ---------------------------------------------------------------- init ----
// Seed hOut[0][s][b][d] = h0[b][s][d]; zero the 128 per-(slot,parity,group) tags.
__global__ void init_kernel(const float* __restrict__ h0, float* __restrict__ hOut0,
                            unsigned int* __restrict__ tags) {
  int i = blockIdx.x * blockDim.x + threadIdx.x;
  const int NH = NS * BB * DIM;              // 65536
  if (i < NH) {
    int s = i >> 13, b = (i >> 10) & 7, d = i & 1023;
    hOut0[i] = h0[((size_t)b * NS + s) * DIM + d];
  }
  if (i < 128) tags[i] = 0u;
}

// ---------------------------------------------------------------- GEMM ----
// Wx[i][d] = sum_k x[i][k] * W[d][k], split-precision bf16 (W = Whi + Wlo).
__global__ __launch_bounds__(256) void gemm_wx(const float* __restrict__ X,
                                               const float* __restrict__ W,
                                               float* __restrict__ Co) {
  __shared__ unsigned short As[128][40];
  __shared__ unsigned short Bh[128][40];
  __shared__ unsigned short Bl[128][40];
  const int bn = blockIdx.x & 7;        // d-tile
  const int bm = blockIdx.x >> 3;       // i-tile
  const int tid = threadIdx.x;
  const int wave = tid >> 6, lane = tid & 63, l15 = lane & 15, quad = lane >> 4;
  const int wm = wave & 1, wn = wave >> 1;
  f4v acc[4][4];
  for (int i = 0; i < 4; ++i)
    for (int j = 0; j < 4; ++j) acc[i][j] = (f4v){0.f, 0.f, 0.f, 0.f};
  const int row = tid >> 1, kh = (tid & 1) * 16;
  const float* srcA = X + ((size_t)(bm * 128 + row)) * DIM + kh;
  const float* srcB = W + ((size_t)(bn * 128 + row)) * DIM + kh;
  for (int k0 = 0; k0 < DIM; k0 += 32) {
    __syncthreads();
    unsigned short ta[16], th[16], tl[16];
    for (int q = 0; q < 16; q += 4) {
      f4v a4 = *(const f4v*)(srcA + k0 + q);
      for (int r2 = 0; r2 < 4; ++r2) ta[q + r2] = f2bf(a4[r2]);
      f4v b4 = *(const f4v*)(srcB + k0 + q);
      for (int r2 = 0; r2 < 4; ++r2) {
        unsigned short hi = f2bf(b4[r2]);
        th[q + r2] = hi;
        tl[q + r2] = f2bf(b4[r2] - bf2f(hi));
      }
    }
    *(s8v*)&As[row][kh] = *(s8v*)&ta[0];
    *(s8v*)&As[row][kh + 8] = *(s8v*)&ta[8];
    *(s8v*)&Bh[row][kh] = *(s8v*)&th[0];
    *(s8v*)&Bh[row][kh + 8] = *(s8v*)&th[8];
    *(s8v*)&Bl[row][kh] = *(s8v*)&tl[0];
    *(s8v*)&Bl[row][kh + 8] = *(s8v*)&tl[8];
    __syncthreads();
    s8v af[4], bhf[4], blf[4];
    for (int i = 0; i < 4; ++i) af[i] = *(const s8v*)&As[wm * 64 + i * 16 + l15][quad * 8];
    for (int j = 0; j < 4; ++j) bhf[j] = *(const s8v*)&Bh[wn * 64 + j * 16 + l15][quad * 8];
    for (int j = 0; j < 4; ++j) blf[j] = *(const s8v*)&Bl[wn * 64 + j * 16 + l15][quad * 8];
    for (int i = 0; i < 4; ++i)
      for (int j = 0; j < 4; ++j) {
        acc[i][j] = __builtin_amdgcn_mfma_f32_16x16x32_bf16(af[i], bhf[j], acc[i][j], 0, 0, 0);
        acc[i][j] = __builtin_amdgcn_mfma_f32_16x16x32_bf16(af[i], blf[j], acc[i][j], 0, 0, 0);
      }
  }
  for (int i = 0; i < 4; ++i)
    for (int j = 0; j < 4; ++j) {
      int ci = bm * 128 + wm * 64 + i * 16 + quad * 4;
      int cd = bn * 128 + wn * 64 + j * 16 + l15;
      for (int r2 = 0; r2 < 4; ++r2)
        Co[((size_t)(ci + r2)) * DIM + cd] = acc[i][j][r2];
    }
}

// ----------------------------------------------------------- recurrence ----
// 8 slots x NG WGs. WG g owns d-slice [g*128, g*128+128).
// Exchange protocol (replaces counter barrier):
//   producer: relaxed agent-scope u64 stores of fp32 value pairs into
//             vx[s][parity][g][b][r]  -> s_waitcnt vmcnt(0) (values at the
//             coherent point) -> __syncthreads -> tid0 stores tag = t+1.
//   consumer: poll the 8 tags of (s,parity) (one 32B line) until all == t+1;
//             values are then guaranteed visible (ordered before the tag by
//             the producer's vmcnt drain); read them and sum fp32 in fixed
//             g2 order (bit-identical numerics to the barrier version).
// Parity double-buffer + monotone tags: a WG can republish a parity buffer
// (tag t+3 over t+1) only after observing every peer's tag t+2, which each
// peer stores only after its end-of-step-t __syncthreads, i.e. after it has
// fully consumed the tag-t+1 values. Max skew = 1 step; no overwrite race.
__global__ __launch_bounds__(256) void seq_kernel(const float* __restrict__ Wx,
                                                  float* __restrict__ hOut,
                                                  const float* __restrict__ bias,
                                                  const float* __restrict__ U,
                                                  const float* __restrict__ V,
                                                  const float* __restrict__ h0,
                                                  float* __restrict__ vx,
                                                  unsigned int* __restrict__ tags) {
  const int s = blockIdx.x & 7;
  const int g = blockIdx.x >> 3;
  const int tid = threadIdx.x;
  const int wave = tid >> 6, lane = tid & 63, l15 = lane & 15, quad = lane >> 4;
  const int d0 = g * DCH;

  __shared__ unsigned short hbuf[16][DCH + 8];    // [b][d_local] bf16 (rows 8..15 junk)
  __shared__ unsigned short vbuf[16][RANK + 8];   // [b][r] bf16 (rows 8..15 junk)

  // ---- persistent weight fragments (fp32 -> bf16), MFMA A-layout ----
  // stage1 A = V rows: m=r, k=d_local. Wave handles 4 M-tiles (64 r), K=128.
  s8v Vfrag[4][4];
  #pragma unroll
  for (int mt = 0; mt < 4; ++mt)
    #pragma unroll
    for (int kk = 0; kk < 4; ++kk) {
      const float* p = V + ((size_t)s * RANK + wave * 64 + mt * 16 + l15) * DIM
                         + d0 + kk * 32 + quad * 8;
      s8v f;
      #pragma unroll
      for (int j = 0; j < 8; ++j) f[j] = (short)f2bf(p[j]);
      Vfrag[mt][kk] = f;
    }
  // stage2 A = U rows: m=d_local, k=r. Wave handles 2 M-tiles (32 d), K=256.
  s8v Ufrag[2][8];
  #pragma unroll
  for (int mt = 0; mt < 2; ++mt)
    #pragma unroll
    for (int kk = 0; kk < 8; ++kk) {
      const float* p = U + ((size_t)s * DIM + d0 + wave * 32 + mt * 16 + l15) * RANK
                         + kk * 32 + quad * 8;
      s8v f;
      #pragma unroll
      for (int j = 0; j < 8; ++j) f[j] = (short)f2bf(p[j]);
      Ufrag[mt][kk] = f;
    }
  float bias4[2][4];
  #pragma unroll
  for (int mt = 0; mt < 2; ++mt)
    #pragma unroll
    for (int r2 = 0; r2 < 4; ++r2)
      bias4[mt][r2] = bias[d0 + wave * 32 + mt * 16 + quad * 4 + r2];

  // seed local h slice from h0
  for (int c = tid; c < BB * DCH; c += 256) {
    int b = c >> 7, dl = c & 127;
    hbuf[b][dl] = f2bf(h0[((size_t)b * NS + s) * DIM + d0 + dl]);
  }
  __syncthreads();

  const int b_ep = l15;             // epilogue / producer batch lane
  const int bpoll = tid >> 5;       // consumer batch row (0..7)
  const int rbase = (tid & 31) * 8; // consumer r-chunk base

  for (int t = 0; t < TSTEPS; ++t) {
    const int buf = t & 1;
    const unsigned want = (unsigned)(t + 1);

    // prefetch Wx for the epilogue (independent; hides under stage1)
    f4v wx4[2];
    if (b_ep < 8) {
      #pragma unroll
      for (int mt = 0; mt < 2; ++mt)
        wx4[mt] = *(const f4v*)&Wx[((size_t)t * BB + b_ep) * DIM + d0 + wave * 32 + mt * 16 + quad * 4];
    }

    // ---- stage 1: partial v over local d-slice (K=128, all in-wave)
    f4v acc1[4];
    #pragma unroll
    for (int mt = 0; mt < 4; ++mt) acc1[mt] = (f4v){0.f, 0.f, 0.f, 0.f};
    #pragma unroll
    for (int kk = 0; kk < 4; ++kk) {
      s8v hfrag = *(const s8v*)&hbuf[l15][kk * 32 + quad * 8];
      #pragma unroll
      for (int mt = 0; mt < 4; ++mt)
        acc1[mt] = __builtin_amdgcn_mfma_f32_16x16x32_bf16(Vfrag[mt][kk], hfrag, acc1[mt], 0, 0, 0);
    }

    // ---- publish partial v: relaxed agent u64 stores, layout [s][buf][g][b][r]
    if (b_ep < 8) {
      unsigned long long* vw = (unsigned long long*)vx
          + ((size_t)(s * 2 + buf) * NG + g) * 1024 + (size_t)b_ep * 128;
      #pragma unroll
      for (int mt = 0; mt < 4; ++mt) {
        int half = wave * 32 + mt * 8 + quad * 2;   // u64 index of r = wave*64+mt*16+quad*4
        union { f2v f; unsigned long long u; } c0, c1;
        c0.f = (f2v){acc1[mt][0], acc1[mt][1]};
        c1.f = (f2v){acc1[mt][2], acc1[mt][3]};
        __hip_atomic_store(vw + half, c0.u, __ATOMIC_RELAXED, __HIP_MEMORY_SCOPE_AGENT);
        __hip_atomic_store(vw + half + 1, c1.u, __ATOMIC_RELAXED, __HIP_MEMORY_SCOPE_AGENT);
      }
    }
    asm volatile("s_waitcnt vmcnt(0)" ::: "memory");  // values at coherent point
    __syncthreads();                                  // all 4 waves drained
    if (tid == 0)
      __hip_atomic_store(tags + (s * 2 + buf) * NG + g, want,
                         __ATOMIC_RELAXED, __HIP_MEMORY_SCOPE_AGENT);

    // ---- poll the 8 group tags (one 32B line), all threads
    {
      const unsigned int* tg = tags + (s * 2 + buf) * NG;
      for (;;) {
        unsigned bad = 0;
        #pragma unroll
        for (int g2 = 0; g2 < NG; ++g2)
          bad |= __hip_atomic_load(tg + g2, __ATOMIC_RELAXED, __HIP_MEMORY_SCOPE_AGENT) ^ want;
        if (!bad) break;
      }
    }
    asm volatile("" ::: "memory");   // pin value loads after the poll

    // ---- gather: read all NG partials, fp32 sum in fixed g2 order, bf16 -> vbuf
    {
      const unsigned long long* vr = (const unsigned long long*)vx
          + ((size_t)(s * 2 + buf) * NG) * 1024 + (size_t)bpoll * 128 + (tid & 31) * 4;
      float sum[8] = {0.f, 0.f, 0.f, 0.f, 0.f, 0.f, 0.f, 0.f};
      #pragma unroll
      for (int g2 = 0; g2 < NG; ++g2) {
        #pragma unroll
        for (int q = 0; q < 4; ++q) {
          unsigned long long u = __hip_atomic_load(vr + (size_t)g2 * 1024 + q,
                                                   __ATOMIC_RELAXED, __HIP_MEMORY_SCOPE_AGENT);
          union { unsigned long long u; f2v f; } c; c.u = u;
          sum[q * 2] += c.f[0];
          sum[q * 2 + 1] += c.f[1];
        }
      }
      s8v v8;
      #pragma unroll
      for (int j = 0; j < 8; ++j) v8[j] = (short)f2bf(sum[j]);
      *(s8v*)&vbuf[bpoll][rbase] = v8;
    }
    __syncthreads();

    // ---- stage 2: u for local d-slice, K = full RANK
    f4v acc2[2];
    acc2[0] = (f4v){0.f, 0.f, 0.f, 0.f};
    acc2[1] = (f4v){0.f, 0.f, 0.f, 0.f};
    #pragma unroll
    for (int kk = 0; kk < 8; ++kk) {
      s8v vfrag = *(const s8v*)&vbuf[l15][kk * 32 + quad * 8];
      acc2[0] = __builtin_amdgcn_mfma_f32_16x16x32_bf16(Ufrag[0][kk], vfrag, acc2[0], 0, 0, 0);
      acc2[1] = __builtin_amdgcn_mfma_f32_16x16x32_bf16(Ufrag[1][kk], vfrag, acc2[1], 0, 0, 0);
    }
    // ---- epilogue: tanh, write hOut (fp32 global) + local hbuf (bf16)
    if (b_ep < 8) {
      #pragma unroll
      for (int mt = 0; mt < 2; ++mt) {
        int dl = wave * 32 + mt * 16 + quad * 4;
        f4v h4;
        s4v hb;
        #pragma unroll
        for (int r2 = 0; r2 < 4; ++r2) {
          float u = acc2[mt][r2] + wx4[mt][r2] + bias4[mt][r2];
          u = fminf(fmaxf(u, -15.f), 15.f);
          float e = __expf(2.f * u);
          float hv = (e - 1.f) / (e + 1.f);
          h4[r2] = hv;
          hb[r2] = (short)f2bf(hv);
        }
        *(f4v*)&hOut[(((size_t)(t + 1) * NS + s) * BB + b_ep) * DIM + d0 + dl] = h4;
        *(s4v*)&hbuf[b_ep][dl] = hb;
      }
    }
    __syncthreads();  // hbuf(t+1) visible to all waves before next stage1
  }
}

// ------------------------------------------------------------- epilogue ----
__global__ void out_kernel(const float* __restrict__ z, const float* __restrict__ h,
                           const float* __restrict__ Cs, float* __restrict__ out) {
  size_t i = (size_t)blockIdx.x * blockDim.x + threadIdx.x;
  const size_t n4 = (size_t)TSTEPS * BB * DIM / 4;
  float c[8];
  for (int s2 = 0; s2 < 8; ++s2) c[s2] = Cs[s2];
  for (; i < n4; i += (size_t)gridDim.x * blockDim.x) {
    size_t base = i * 4;
    size_t t = base / (BB * DIM);
    size_t rem = base % (BB * DIM);
    f4v accv = (f4v){0.f, 0.f, 0.f, 0.f};
    for (int s2 = 0; s2 < 8; ++s2) {
      f4v hv = *(const f4v*)&h[((t + 1) * NS + s2) * (size_t)(BB * DIM) + rem];
      accv += hv * c[s2];
    }
    f4v zv = *(const f4v*)&z[base];
    f4v o;
    for (int r2 = 0; r2 < 4; ++r2) {
      float zz = zv[r2];
      float sil = zz / (1.f + __expf(-zz));
      o[r2] = accv[r2] * sil;
    }
    *(f4v*)&out[base] = o;
  }
}

// ---------------------------------------------------------------- launch ----
extern "C" void kernel_launch(void* const* d_in, const int* in_sizes, int n_in,
                              void* d_out, int out_size, void* d_ws, size_t ws_size,
                              hipStream_t stream) {
  const float* x  = (const float*)d_in[0];   // [T,B,D]
  const float* z  = (const float*)d_in[1];   // [T,B,D]
  const float* h0 = (const float*)d_in[2];   // [B,S,D]
  const float* Wm = (const float*)d_in[3];   // [D,D]
  const float* U  = (const float*)d_in[4];   // [S,D,R]
  const float* V  = (const float*)d_in[5];   // [S,R,D]
  const float* bs = (const float*)d_in[6];   // [D]
  const float* Cs = (const float*)d_in[7];   // [S]

  float* out  = (float*)d_out;                       // [T,B,D]
  float* hOut = out + (size_t)TSTEPS * BB * DIM;     // [T+1,S,B,D]

  // workspace: identical footprint to the proven baseline (1 MB + 512 B)
  float* vx = (float*)d_ws;                               // S*2*NG*B*R fp32 = 1 MB
  unsigned int* tags = (unsigned int*)(vx + (size_t)NS * 2 * NG * BB * RANK);  // 128 u32

  float* Wx = out;  // reuse `out` region as Wx scratch (overwritten by out_kernel)

  init_kernel<<<256, 256, 0, stream>>>(h0, hOut, tags);
  gemm_wx<<<512, 256, 0, stream>>>(x, Wm, Wx);
  seq_kernel<<<64, 256, 0, stream>>>(Wx, hOut, bs, U, V, h0, vx, tags);
  out_kernel<<<2048, 256, 0, stream>>>(z, hOut, Cs, out);
}